// Round 1
// baseline (164.487 us; speedup 1.0000x reference)
//
#include <hip/hip_runtime.h>
#include <cmath>

#define TW 32
#define TH 32
#define HR (TH + 10)     // 42 rows of h-pass results
#define IMG 512
#define SSIM_C1 1e-4f
#define SSIM_C2 9e-4f

struct GaussWin { float g[11]; };

typedef float v2f __attribute__((ext_vector_type(2)));

// Native packed fp32: clang/LLVM selects v_pk_fma_f32 / v_pk_mul_f32 for
// <2 x float> on gfx90a+ (HasPackedFP32Ops).
__device__ __forceinline__ v2f pk_fma(v2f a, v2f b, v2f c) {
    return __builtin_elementwise_fma(a, b, c);
}
__device__ __forceinline__ v2f pk_mul(v2f a, v2f b) { return a * b; }

// TH=32: LDS = 42*32*20 + 64 = 26944 B -> 6 blocks/CU (was 37 KB -> 4).
// Occupancy cap 16 -> 24 waves/CU; measured VALUBusy was 70% with 30% idle,
// i.e. latency-bound, so we buy concurrency with a slightly worse halo ratio.
__launch_bounds__(256, 6)
__global__ void ssim_tile_kernel(const float* __restrict__ x,
                                 const float* __restrict__ y,
                                 const float* __restrict__ conf,
                                 float* __restrict__ partials,
                                 float* __restrict__ out,
                                 int use_ws, float scale,
                                 GaussWin W) {
    __shared__ float4 s_h4[HR * TW];    // 21504 B  (mu_x, mu_y, sxx, syy)
    __shared__ float  s_h1[HR * TW];    //  5376 B  (sxy)
    __shared__ float  s_red[4];         // total 26944 B -> 6 blocks/CU

    const int tid = threadIdx.x;
    const int plane = blockIdx.z;              // b*3 + c
    const int tx0 = blockIdx.x * TW;
    const int ty0 = blockIdx.y * TH;
    const int pbase = plane * (IMG * IMG);
    const int cbase = (plane / 3) * (IMG * IMG);

    // Gaussian symmetric: g[k] == g[10-k] bitwise. 6 distinct packed weights.
    constexpr int WI[11] = {0,1,2,3,4,5,4,3,2,1,0};
    v2f w2[6];
    #pragma unroll
    for (int i = 0; i < 6; i++) w2[i] = (v2f){W.g[i], W.g[i]};

    // Interior blocks touch no image border anywhere in the halo window.
    // TH=32: rows [ty0-5, ty0+36] in-bounds iff 1 <= by <= 14.
    const bool interior = (blockIdx.x >= 1) & (blockIdx.x <= 14) &
                          (blockIdx.y >= 1) & (blockIdx.y <= 14);

    // ---- Phase 1: horizontal pass, direct from global ----
    // 42 rows x 4 col-groups = 168 strips, one per thread. Wave 3 (tid>=192)
    // skips this phase entirely (execz) -> no extra wave-instruction cost.
    // Strip = 8 output cols; reads 6 aligned float4s per array covering cols
    // [cs-8, cs+16); elements 3..20 are the 18 taps. 16B-aligned reads are
    // fully in- or out-of-bounds -> exact zero padding.
    if (tid < HR * 4) {
        const int r = tid >> 2;
        const int cs = (tid & 3) * 8;
        const int gy = ty0 - 5 + r;
        const float* xrow = x + pbase + gy * IMG;
        const float* yrow = y + pbase + gy * IMG;
        const int c0 = tx0 + cs - 8;

        float4 fx[6], fy[6];
        if (interior) {
            #pragma unroll
            for (int q = 0; q < 6; q++) {
                fx[q] = *(const float4*)(xrow + c0 + 4 * q);
                fy[q] = *(const float4*)(yrow + c0 + 4 * q);
            }
        } else {
            const bool rowok = ((unsigned)gy < IMG);
            #pragma unroll
            for (int q = 0; q < 6; q++) {
                int col = c0 + 4 * q;
                fx[q] = make_float4(0.f, 0.f, 0.f, 0.f);
                fy[q] = make_float4(0.f, 0.f, 0.f, 0.f);
                if (rowok && (unsigned)col <= (unsigned)(IMG - 4)) {
                    fx[q] = *(const float4*)(xrow + col);
                    fy[q] = *(const float4*)(yrow + col);
                }
            }
        }
        float vxa[24], vya[24];
        #pragma unroll
        for (int q = 0; q < 6; q++) {
            vxa[4*q+0]=fx[q].x; vxa[4*q+1]=fx[q].y; vxa[4*q+2]=fx[q].z; vxa[4*q+3]=fx[q].w;
            vya[4*q+0]=fy[q].x; vya[4*q+1]=fy[q].y; vya[4*q+2]=fy[q].z; vya[4*q+3]=fy[q].w;
        }

        // Streaming tap-major conv.
        v2f amu[8], as2[8];
        float axy[8];
        #pragma unroll
        for (int j = 0; j < 8; j++) { amu[j]=(v2f){0.f,0.f}; as2[j]=(v2f){0.f,0.f}; axy[j]=0.f; }
        #pragma unroll
        for (int k = 0; k < 18; k++) {
            float xv = vxa[k + 3], yv = vya[k + 3];
            v2f xy = (v2f){xv, yv};
            v2f p2 = pk_mul(xy, xy);          // (x^2, y^2)
            float pxy = xv * yv;
            const int jlo = (k - 10 > 0) ? (k - 10) : 0;
            const int jhi = (k < 7) ? k : 7;
            #pragma unroll
            for (int j = jlo; j <= jhi; j++) {
                v2f w = w2[WI[k - j]];
                amu[j] = pk_fma(xy, w, amu[j]);
                as2[j] = pk_fma(p2, w, as2[j]);
                axy[j] = fmaf(pxy, w.x, axy[j]);
            }
        }
        const int quad = cs & 24;
        const int base0 = cs + 2 * (cs >> 3) + 5 * r;
        #pragma unroll
        for (int j = 0; j < 8; j++) {
            int pc = quad | ((base0 + j) & 7);
            s_h4[r * TW + pc] = make_float4(amu[j].x, amu[j].y, as2[j].x, as2[j].y);
            s_h1[r * TW + pc] = axy[j];
        }
    }

    // Prefetch conf (consumed in epilogue) before the barrier.
    // 16x32 grid covers 512 rows exactly -> no bounds guard needed.
    const int c  = tid & 31;
    const int r0 = (tid >> 5) * 4;            // 8 groups x 4 rows = 32 rows
    float cf[4];
    #pragma unroll
    for (int j = 0; j < 4; j++) {
        cf[j] = conf[cbase + (ty0 + r0 + j) * IMG + tx0 + c];
    }
    __syncthreads();

    // Weight-pair table for the cross-output-packed sxy conv:
    // wp[d] = (g'[d], g'[d-1]) with g'[i]=g[i] for 0..10 else 0.
    // Built AFTER the barrier so it doesn't raise phase-1 register pressure.
    float ge[12];
    #pragma unroll
    for (int i = 0; i < 11; i++) ge[i] = W.g[WI[i]];
    ge[11] = 0.f;
    v2f wp[12];
    #pragma unroll
    for (int d = 0; d < 12; d++) wp[d] = (v2f){ ge[d], (d == 0) ? 0.f : ge[d - 1] };

    // ---- Phase 2: vertical pass, 4 vertically-adjacent outputs per thread ----
    v2f amu[4], as2[4], axy2[2];
    #pragma unroll
    for (int j = 0; j < 4; j++) { amu[j]=(v2f){0.f,0.f}; as2[j]=(v2f){0.f,0.f}; }
    axy2[0] = (v2f){0.f, 0.f};
    axy2[1] = (v2f){0.f, 0.f};

    const int cquad = c & 24;
    const int cb0 = c + 2 * (c >> 3) + 5 * r0;
    #pragma unroll
    for (int t = 0; t < 14; t++) {
        int row = r0 + t;
        int pc = cquad | ((cb0 + 5 * t) & 7);
        float4 h4 = s_h4[row * TW + pc];
        float  h1 = s_h1[row * TW + pc];
        v2f hmu = (v2f){h4.x, h4.y};
        v2f hs2 = (v2f){h4.z, h4.w};
        #pragma unroll
        for (int j = 0; j < 4; j++) {
            int k = t - j;                    // constant post-unroll
            if (k >= 0 && k <= 10) {
                v2f w = w2[WI[k]];
                amu[j] = pk_fma(hmu, w, amu[j]);
                as2[j] = pk_fma(hs2, w, as2[j]);
            }
        }
        // sxy conv packed across output pairs: axy2[p] covers j=2p (lo), 2p+1 (hi)
        v2f h1b = (v2f){h1, h1};
        #pragma unroll
        for (int p = 0; p < 2; p++) {
            int d = t - 2 * p;                // weight-pair index, constant post-unroll
            if (d >= 0 && d <= 11) {
                axy2[p] = pk_fma(h1b, wp[d], axy2[p]);
            }
        }
    }

    // ---- Epilogue: SSIM + conf weighting + accumulate ----
    float lsum = 0.f;
    #pragma unroll
    for (int j = 0; j < 4; j++) {
        float mu_x = amu[j].x, mu_y = amu[j].y;
        float axyj = (j & 1) ? axy2[j >> 1].y : axy2[j >> 1].x;
        v2f prod = pk_mul(amu[j], amu[j]);    // (mu_x^2, mu_y^2)
        float mu_xy = mu_x * mu_y;
        v2f sig = as2[j] - prod;              // (sigma_x^2, sigma_y^2), packed
        float sigxy = axyj - mu_xy;
        float num = fmaf(2.f, mu_xy, SSIM_C1) * fmaf(2.f, sigxy, SSIM_C2);
        float den = (prod.x + prod.y + SSIM_C1) * (sig.x + sig.y + SSIM_C2);
        float ssim = num * __builtin_amdgcn_rcpf(den);   // den >= C1*C2 > 0
        float loss = fminf(fmaxf(1.f - ssim, 0.f), 1.f);
        lsum = fmaf(loss, cf[j], lsum);
    }

    // ---- Block reduction ----
    #pragma unroll
    for (int off = 32; off; off >>= 1) lsum += __shfl_down(lsum, off, 64);
    if ((tid & 63) == 0) s_red[tid >> 6] = lsum;
    __syncthreads();
    if (tid == 0) {
        float t = s_red[0] + s_red[1] + s_red[2] + s_red[3];
        if (use_ws) {
            partials[blockIdx.x + gridDim.x * (blockIdx.y + gridDim.y * blockIdx.z)] = t;
        } else {
            atomicAdd(out, t * scale);
        }
    }
}

// Single-block reduce: writes out[0] directly (no memset, no atomics).
__global__ void reduce_kernel(const float* __restrict__ partials, int n,
                              float* __restrict__ out, float scale) {
    __shared__ float s_red[16];
    float s = 0.f;
    const float4* p4 = (const float4*)partials;
    const int n4 = n >> 2;
    for (int i = threadIdx.x; i < n4; i += 1024) {
        float4 v = p4[i];
        s += (v.x + v.y) + (v.z + v.w);
    }
    for (int i = (n4 << 2) + threadIdx.x; i < n; i += 1024) s += partials[i];
    #pragma unroll
    for (int off = 32; off; off >>= 1) s += __shfl_down(s, off, 64);
    if ((threadIdx.x & 63) == 0) s_red[threadIdx.x >> 6] = s;
    __syncthreads();
    if (threadIdx.x == 0) {
        float t = 0.f;
        #pragma unroll
        for (int i = 0; i < 16; i++) t += s_red[i];
        out[0] = t * scale;
    }
}

extern "C" void kernel_launch(void* const* d_in, const int* in_sizes, int n_in,
                              void* d_out, int out_size, void* d_ws, size_t ws_size,
                              hipStream_t stream) {
    const float* x    = (const float*)d_in[0];
    const float* y    = (const float*)d_in[1];
    const float* conf = (const float*)d_in[2];
    float* out = (float*)d_out;
    float* partials = (float*)d_ws;

    // Gaussian window, computed like the reference: float64 exp + normalize, cast f32
    GaussWin W;
    {
        double gd[11], s = 0.0;
        for (int i = 0; i < 11; i++) { gd[i] = exp(-((i - 5) * (i - 5)) / 4.5); s += gd[i]; }
        for (int i = 0; i < 11; i++) W.g[i] = (float)(gd[i] / s);
    }

    const int B = 16, C = 3;
    const float scale = 1.0f / (float)(B * C * IMG * IMG);
    dim3 grid(IMG / TW, IMG / TH, B * C);                   // 16 x 16 x 48 = 12288 blocks
    const int nblocks = (IMG / TW) * (IMG / TH) * B * C;
    const int use_ws = (ws_size >= (size_t)nblocks * sizeof(float)) ? 1 : 0;

    if (!use_ws) {
        // fallback: atomic accumulation into d_out (poisoned before each call)
        hipMemsetAsync(d_out, 0, sizeof(float), stream);
    }
    ssim_tile_kernel<<<grid, 256, 0, stream>>>(x, y, conf, partials, out, use_ws, scale, W);
    if (use_ws) {
        reduce_kernel<<<1, 1024, 0, stream>>>(partials, nblocks, out, scale);
    }
}

// Round 2
// 156.044 us; speedup vs baseline: 1.0541x; 1.0541x over previous
//
#include <hip/hip_runtime.h>
#include <cmath>

#define TW 32
#define TH 32
#define HR (TH + 10)     // 42 rows of h-pass results
#define IMG 512
#define SSIM_C1 1e-4f
#define SSIM_C2 9e-4f

struct GaussWin { float g[11]; };

typedef float v2f __attribute__((ext_vector_type(2)));

// Native packed fp32: clang/LLVM selects v_pk_fma_f32 for <2 x float> on
// gfx90a+ (HasPackedFP32Ops).
__device__ __forceinline__ v2f pk_fma(v2f a, v2f b, v2f c) {
    return __builtin_elementwise_fma(a, b, c);
}

// 4-field formulation: SSIM only needs sigma_x^2 + sigma_y^2 (never each
// separately), and conv is linear, so we convolve s2 = x^2 + y^2 instead of
// x^2 and y^2. Fields (mu_x, mu_y, s2, sxy) = exactly two v2f accumulators:
//   pair A = (x, y), pair B = (x^2+y^2, x*y)
// => 2 pk_fma per output-tap in BOTH passes (was 2 pk + 1 scalar), and the
// h-pass result is a single float4 (16 B vs 20 B) -> LDS 21.6 KB -> 7 blk/CU.
__launch_bounds__(256, 7)
__global__ void ssim_tile_kernel(const float* __restrict__ x,
                                 const float* __restrict__ y,
                                 const float* __restrict__ conf,
                                 float* __restrict__ partials,
                                 float* __restrict__ out,
                                 int use_ws, float scale,
                                 GaussWin W) {
    __shared__ float4 s_h[HR * TW];     // 21504 B  (mu_x, mu_y, s2, sxy)
    __shared__ float  s_red[4];         // total ~21.6 KB -> 7 blocks/CU

    const int tid = threadIdx.x;
    const int plane = blockIdx.z;              // b*3 + c
    const int tx0 = blockIdx.x * TW;
    const int ty0 = blockIdx.y * TH;
    const int pbase = plane * (IMG * IMG);
    const int cbase = (plane / 3) * (IMG * IMG);

    // Gaussian symmetric: g[k] == g[10-k] bitwise. 6 distinct packed weights.
    constexpr int WI[11] = {0,1,2,3,4,5,4,3,2,1,0};
    v2f w2[6];
    #pragma unroll
    for (int i = 0; i < 6; i++) w2[i] = (v2f){W.g[i], W.g[i]};

    // Interior blocks touch no image border anywhere in the halo window.
    // TH=32: rows [ty0-5, ty0+36] in-bounds iff 1 <= by <= 14.
    const bool interior = (blockIdx.x >= 1) & (blockIdx.x <= 14) &
                          (blockIdx.y >= 1) & (blockIdx.y <= 14);

    // ---- Phase 1: horizontal pass, direct from global ----
    // 42 rows x 4 col-groups = 168 strips, one per thread. Wave 3 skips this
    // phase entirely (execz). Strip = 8 output cols; reads 6 aligned float4s
    // per array covering cols [cs-8, cs+16); elements 3..20 are the 18 taps.
    // 16B-aligned reads are fully in- or out-of-bounds -> exact zero padding.
    if (tid < HR * 4) {
        const int r = tid >> 2;
        const int cs = (tid & 3) * 8;
        const int gy = ty0 - 5 + r;
        const float* xrow = x + pbase + gy * IMG;
        const float* yrow = y + pbase + gy * IMG;
        const int c0 = tx0 + cs - 8;

        float4 fx[6], fy[6];
        if (interior) {
            #pragma unroll
            for (int q = 0; q < 6; q++) {
                fx[q] = *(const float4*)(xrow + c0 + 4 * q);
                fy[q] = *(const float4*)(yrow + c0 + 4 * q);
            }
        } else {
            const bool rowok = ((unsigned)gy < IMG);
            #pragma unroll
            for (int q = 0; q < 6; q++) {
                int col = c0 + 4 * q;
                fx[q] = make_float4(0.f, 0.f, 0.f, 0.f);
                fy[q] = make_float4(0.f, 0.f, 0.f, 0.f);
                if (rowok && (unsigned)col <= (unsigned)(IMG - 4)) {
                    fx[q] = *(const float4*)(xrow + col);
                    fy[q] = *(const float4*)(yrow + col);
                }
            }
        }
        float vxa[24], vya[24];
        #pragma unroll
        for (int q = 0; q < 6; q++) {
            vxa[4*q+0]=fx[q].x; vxa[4*q+1]=fx[q].y; vxa[4*q+2]=fx[q].z; vxa[4*q+3]=fx[q].w;
            vya[4*q+0]=fy[q].x; vya[4*q+1]=fy[q].y; vya[4*q+2]=fy[q].z; vya[4*q+3]=fy[q].w;
        }

        // Streaming tap-major conv over the two packed accumulators.
        v2f amu[8], a2[8];
        #pragma unroll
        for (int j = 0; j < 8; j++) { amu[j]=(v2f){0.f,0.f}; a2[j]=(v2f){0.f,0.f}; }
        #pragma unroll
        for (int k = 0; k < 18; k++) {
            float xv = vxa[k + 3], yv = vya[k + 3];
            v2f xy = (v2f){xv, yv};
            v2f p2 = xy * xy;                     // (x^2, y^2)
            v2f zw = (v2f){p2.x + p2.y, xv * yv}; // (x^2+y^2, x*y)
            const int jlo = (k - 10 > 0) ? (k - 10) : 0;
            const int jhi = (k < 7) ? k : 7;
            #pragma unroll
            for (int j = jlo; j <= jhi; j++) {
                v2f w = w2[WI[k - j]];
                amu[j] = pk_fma(xy, w, amu[j]);
                a2[j]  = pk_fma(zw, w, a2[j]);
            }
        }
        const int quad = cs & 24;
        const int base0 = cs + 2 * (cs >> 3) + 5 * r;
        #pragma unroll
        for (int j = 0; j < 8; j++) {
            int pc = quad | ((base0 + j) & 7);
            s_h[r * TW + pc] = make_float4(amu[j].x, amu[j].y, a2[j].x, a2[j].y);
        }
    }

    // Prefetch conf (consumed in epilogue) before the barrier.
    // 16x16 grid covers 512 rows exactly -> no bounds guard needed.
    const int c  = tid & 31;
    const int r0 = (tid >> 5) * 4;            // 8 groups x 4 rows = 32 rows
    float cf[4];
    #pragma unroll
    for (int j = 0; j < 4; j++) {
        cf[j] = conf[cbase + (ty0 + r0 + j) * IMG + tx0 + c];
    }
    __syncthreads();

    // ---- Phase 2: vertical pass, 4 vertically-adjacent outputs per thread ----
    v2f amu[4], a2[4];
    #pragma unroll
    for (int j = 0; j < 4; j++) { amu[j]=(v2f){0.f,0.f}; a2[j]=(v2f){0.f,0.f}; }

    const int cquad = c & 24;
    const int cb0 = c + 2 * (c >> 3) + 5 * r0;
    #pragma unroll
    for (int t = 0; t < 14; t++) {
        int row = r0 + t;
        int pc = cquad | ((cb0 + 5 * t) & 7);
        float4 h4 = s_h[row * TW + pc];
        v2f hmu = (v2f){h4.x, h4.y};
        v2f h2  = (v2f){h4.z, h4.w};
        #pragma unroll
        for (int j = 0; j < 4; j++) {
            int k = t - j;                    // constant post-unroll
            if (k >= 0 && k <= 10) {
                v2f w = w2[WI[k]];
                amu[j] = pk_fma(hmu, w, amu[j]);
                a2[j]  = pk_fma(h2, w, a2[j]);
            }
        }
    }

    // ---- Epilogue: SSIM + conf weighting + accumulate ----
    float lsum = 0.f;
    #pragma unroll
    for (int j = 0; j < 4; j++) {
        float mu_x = amu[j].x, mu_y = amu[j].y;
        v2f prod = amu[j] * amu[j];           // (mu_x^2, mu_y^2), packed
        float mu_xy = mu_x * mu_y;
        float musq  = prod.x + prod.y;        // mu_x^2 + mu_y^2
        float sigsum = a2[j].x - musq;        // sigma_x^2 + sigma_y^2
        float sigxy  = a2[j].y - mu_xy;
        float num = fmaf(2.f, mu_xy, SSIM_C1) * fmaf(2.f, sigxy, SSIM_C2);
        float den = (musq + SSIM_C1) * (sigsum + SSIM_C2);
        float ssim = num * __builtin_amdgcn_rcpf(den);   // den >= C1*C2 > 0
        float loss = fminf(fmaxf(1.f - ssim, 0.f), 1.f);
        lsum = fmaf(loss, cf[j], lsum);
    }

    // ---- Block reduction ----
    #pragma unroll
    for (int off = 32; off; off >>= 1) lsum += __shfl_down(lsum, off, 64);
    if ((tid & 63) == 0) s_red[tid >> 6] = lsum;
    __syncthreads();
    if (tid == 0) {
        float t = s_red[0] + s_red[1] + s_red[2] + s_red[3];
        if (use_ws) {
            partials[blockIdx.x + gridDim.x * (blockIdx.y + gridDim.y * blockIdx.z)] = t;
        } else {
            atomicAdd(out, t * scale);
        }
    }
}

// Single-block reduce: writes out[0] directly (no memset, no atomics).
__global__ void reduce_kernel(const float* __restrict__ partials, int n,
                              float* __restrict__ out, float scale) {
    __shared__ float s_red[16];
    float s = 0.f;
    const float4* p4 = (const float4*)partials;
    const int n4 = n >> 2;
    for (int i = threadIdx.x; i < n4; i += 1024) {
        float4 v = p4[i];
        s += (v.x + v.y) + (v.z + v.w);
    }
    for (int i = (n4 << 2) + threadIdx.x; i < n; i += 1024) s += partials[i];
    #pragma unroll
    for (int off = 32; off; off >>= 1) s += __shfl_down(s, off, 64);
    if ((threadIdx.x & 63) == 0) s_red[threadIdx.x >> 6] = s;
    __syncthreads();
    if (threadIdx.x == 0) {
        float t = 0.f;
        #pragma unroll
        for (int i = 0; i < 16; i++) t += s_red[i];
        out[0] = t * scale;
    }
}

extern "C" void kernel_launch(void* const* d_in, const int* in_sizes, int n_in,
                              void* d_out, int out_size, void* d_ws, size_t ws_size,
                              hipStream_t stream) {
    const float* x    = (const float*)d_in[0];
    const float* y    = (const float*)d_in[1];
    const float* conf = (const float*)d_in[2];
    float* out = (float*)d_out;
    float* partials = (float*)d_ws;

    // Gaussian window, computed like the reference: float64 exp + normalize, cast f32
    GaussWin W;
    {
        double gd[11], s = 0.0;
        for (int i = 0; i < 11; i++) { gd[i] = exp(-((i - 5) * (i - 5)) / 4.5); s += gd[i]; }
        for (int i = 0; i < 11; i++) W.g[i] = (float)(gd[i] / s);
    }

    const int B = 16, C = 3;
    const float scale = 1.0f / (float)(B * C * IMG * IMG);
    dim3 grid(IMG / TW, IMG / TH, B * C);                   // 16 x 16 x 48 = 12288 blocks
    const int nblocks = (IMG / TW) * (IMG / TH) * B * C;
    const int use_ws = (ws_size >= (size_t)nblocks * sizeof(float)) ? 1 : 0;

    if (!use_ws) {
        // fallback: atomic accumulation into d_out (poisoned before each call)
        hipMemsetAsync(d_out, 0, sizeof(float), stream);
    }
    ssim_tile_kernel<<<grid, 256, 0, stream>>>(x, y, conf, partials, out, use_ws, scale, W);
    if (use_ws) {
        reduce_kernel<<<1, 1024, 0, stream>>>(partials, nblocks, out, scale);
    }
}